// Round 7
// baseline (271.125 us; speedup 1.0000x reference)
//
#include <hip/hip_runtime.h>

// Problem constants
#define BI    1152   // B*N = 32*36
#define NREG  36
#define DD    2048
#define RR    512
#define KK    1024   // 2*R
#define ZROWS (BI*NREG)        // 41472
#define MBLK  144              // 4 bi, rows interleaved j*4+g
#define NBLK  128
#define ABUF  (MBLK*32)        // 4608 elems (9 KB) -- A tile per kstep

typedef __bf16 bf16;
typedef __bf16 bf16x8 __attribute__((ext_vector_type(8)));
typedef __bf16 bf16x4 __attribute__((ext_vector_type(4)));
typedef float  f32x4  __attribute__((ext_vector_type(4)));

__device__ __forceinline__ void gl_lds16(const void* g, void* l) {
  __builtin_amdgcn_global_load_lds(
      (const __attribute__((address_space(1))) unsigned int*)g,
      (__attribute__((address_space(3))) unsigned int*)l, 16, 0, 0);
}

// ---------------- fused prep: cvt_mm + transpose_uv + transpose_pt + uvcoord -------
__global__ void k_prep(const float* __restrict__ mm, const float* __restrict__ coords,
                       const float* __restrict__ U_feat, const float* __restrict__ V_feat,
                       const float* __restrict__ P_feat, const float* __restrict__ U_coord,
                       const float* __restrict__ V_coord, const float* __restrict__ P_coord,
                       bf16* __restrict__ mmb, bf16* __restrict__ UT, bf16* __restrict__ VT,
                       bf16* __restrict__ PTt, float* __restrict__ uc, float* __restrict__ vc) {
  __shared__ float tile[32][33];
  int bid = blockIdx.x, tid = threadIdx.x;
  if (bid < 2304) {
    int i = bid * 256 + tid;
    float4 v = ((const float4*)mm)[i];
    bf16x4 o = {(bf16)v.x, (bf16)v.y, (bf16)v.z, (bf16)v.w};
    ((bf16x4*)mmb)[i] = o;
  } else if (bid < 4352) {
    int rel = bid - 2304;
    int zz = rel >> 10, rr = rel & 1023;
    int c0 = (rr & 15) * 32, r0 = (rr >> 4) * 32;     // cols 512, rows 2048
    const float* in = zz ? V_feat : U_feat;
    bf16* outp = zz ? VT : UT;
    int tx = tid & 31, ty = tid >> 5;
#pragma unroll
    for (int k = 0; k < 4; k++)
      tile[ty + 8 * k][tx] = in[(long)(r0 + ty + 8 * k) * 512 + c0 + tx];
    __syncthreads();
#pragma unroll
    for (int k = 0; k < 4; k++)
      outp[(long)(c0 + ty + 8 * k) * 2048 + r0 + tx] = (bf16)tile[tx][ty + 8 * k];
  } else if (bid < 6400) {
    int rel = bid - 4352;
    int zz = rel >> 10, rr = rel & 1023;
    int c0 = (rr & 63) * 32, r0 = (rr >> 6) * 32;     // cols 2048, rows 512
    const float* in = zz ? P_feat : P_coord;
    int koff = zz * 512;
    int tx = tid & 31, ty = tid >> 5;
#pragma unroll
    for (int k = 0; k < 4; k++)
      tile[ty + 8 * k][tx] = in[(long)(r0 + ty + 8 * k) * 2048 + c0 + tx];
    __syncthreads();
    int kc = (koff + r0) >> 5;
#pragma unroll
    for (int k = 0; k < 4; k++) {
      int d = c0 + ty + 8 * k;
      PTt[((long)kc * 2048 + d) * 32 + tx] = (bf16)tile[tx][ty + 8 * k];
    }
  } else {
    int g = bid - 6400;
    float c0 = coords[g * 4 + 0], c1 = coords[g * 4 + 1];
    float c2 = coords[g * 4 + 2], c3 = coords[g * 4 + 3];
#pragma unroll
    for (int i = 0; i < 2; i++) {
      int r = tid + i * 256;
      uc[g * RR + r] = c0 * U_coord[r] + c1 * U_coord[RR + r] + c2 * U_coord[2 * RR + r] + c3 * U_coord[3 * RR + r];
      vc[g * RR + r] = c0 * V_coord[r] + c1 * V_coord[RR + r] + c2 * V_coord[2 * RR + r] + c3 * V_coord[3 * RR + r];
    }
  }
}

// ------- stage 3: uf/vf partials (split-K=2), 64x128 tile, dbuf -------
__launch_bounds__(256)
__global__ void k_gemm_uv(const bf16* __restrict__ mmb, const bf16* __restrict__ UT,
                          const bf16* __restrict__ VT, float* __restrict__ uf,
                          float* __restrict__ vf, float* __restrict__ uf2,
                          float* __restrict__ vf2) {
  __shared__ bf16 lds2[2][6144];   // per buf: A 64x32 (2048) + B 128x32 (4096)
  int uv = blockIdx.z >> 1, kh = blockIdx.z & 1;
  const bf16* Bmat = uv ? VT : UT;
  float* outp = uv ? (kh ? vf2 : vf) : (kh ? uf2 : uf);
  int m0 = blockIdx.x * 64, n0 = blockIdx.y * 128;
  int kbase = kh * 1024;
  int tid = threadIdx.x, wave = tid >> 6, lane = tid & 63;
  int l15 = lane & 15, qv = lane >> 4;
  int qp_c = qv ^ ((l15 >> 1) & 3);
  int qs = (lane & 3) ^ ((lane >> 3) & 3);

  const bf16* gA = mmb + (long)(m0 + wave * 16 + (lane >> 2)) * 2048 + kbase + qs * 8;
  const bf16* gB = Bmat + (long)(n0 + wave * 32 + (lane >> 2)) * 2048 + kbase + qs * 8;
  int lA = wave * 512;
  int lB = 2048 + wave * 1024;

  auto stage = [&](int buf, int k0) {
    bf16* db = &lds2[buf][0];
    gl_lds16(gA + k0, db + lA);
    gl_lds16(gB + k0, db + lB);
    gl_lds16(gB + 16 * 2048 + k0, db + lB + 512);
  };

  f32x4 acc[4][2] = {};
  stage(0, 0);
  for (int k0 = 0; k0 < 1024; k0 += 32) {
    int cur = (k0 >> 5) & 1;
    __syncthreads();
    if (k0 + 32 < 1024) stage(cur ^ 1, k0 + 32);
    bf16x8 a[4], b[2];
#pragma unroll
    for (int mt = 0; mt < 4; mt++)
      a[mt] = *(const bf16x8*)(&lds2[cur][0] + (mt * 16 + l15) * 32 + qp_c * 8);
#pragma unroll
    for (int nt = 0; nt < 2; nt++)
      b[nt] = *(const bf16x8*)(&lds2[cur][2048] + (wave * 32 + nt * 16 + l15) * 32 + qp_c * 8);
#pragma unroll
    for (int mt = 0; mt < 4; mt++)
#pragma unroll
      for (int nt = 0; nt < 2; nt++)
        acc[mt][nt] = __builtin_amdgcn_mfma_f32_16x16x32_bf16(a[mt], b[nt], acc[mt][nt], 0, 0, 0);
  }
#pragma unroll
  for (int mt = 0; mt < 4; mt++)
#pragma unroll
    for (int nt = 0; nt < 2; nt++)
#pragma unroll
      for (int r = 0; r < 4; r++) {
        int row = m0 + mt * 16 + qv * 4 + r;
        int col = n0 + wave * 32 + nt * 16 + l15;
        outp[(long)row * RR + col] = acc[mt][nt][r];
      }
}

// ------- stage 4: z_t[kc][row'][32], row' = (bi>>2)*144 + j*4 + (bi&3) -------
__global__ void k_build_z(const float* __restrict__ uc, const float* __restrict__ vc,
                          const float* __restrict__ uf, const float* __restrict__ vf,
                          const float* __restrict__ uf2, const float* __restrict__ vf2,
                          bf16* __restrict__ z) {
  __shared__ float uL[36 * 128];
  __shared__ float vL[36 * 128];
  int kq = blockIdx.x, b = blockIdx.y, tid = threadIdx.x;
  int kb = (kq & 3) * 128;
  for (int i = tid; i < 1152; i += 256) {
    int row = i >> 5, kk = (i & 31) * 4;
    long src = (long)(b * 36 + row) * RR + kb + kk;
    float4 u4, v4;
    if (kq < 4) {
      u4 = *(const float4*)(uc + src);
      v4 = *(const float4*)(vc + src);
    } else {
      float4 a1 = *(const float4*)(uf + src), a2 = *(const float4*)(uf2 + src);
      float4 b1 = *(const float4*)(vf + src), b2 = *(const float4*)(vf2 + src);
      u4.x = a1.x + a2.x; u4.y = a1.y + a2.y; u4.z = a1.z + a2.z; u4.w = a1.w + a2.w;
      v4.x = b1.x + b2.x; v4.y = b1.y + b2.y; v4.z = b1.z + b2.z; v4.w = b1.w + b2.w;
    }
    *(float4*)&uL[row * 128 + kk] = u4;
    *(float4*)&vL[row * 128 + kk] = v4;
  }
  __syncthreads();
  int cbase = blockIdx.z * 5184;
  for (int c = cbase + tid; c < cbase + 5184; c += 256) {
    int kcl = c / 10368;
    int rem = c - kcl * 10368;
    int row = rem >> 3;             // 0..1295 = gl*36 + j
    int x4 = rem & 7;
    int gl = row / 36;
    int j = row - gl * 36;
    int kl = kcl * 32 + x4 * 4;
    float4 u4 = *(const float4*)&uL[gl * 128 + kl];
    float4 v4 = *(const float4*)&vL[j * 128 + kl];
    float x0 = fmaxf(u4.x * v4.x, 0.f), x1 = fmaxf(u4.y * v4.y, 0.f);
    float x2 = fmaxf(u4.z * v4.z, 0.f), x3 = fmaxf(u4.w * v4.w, 0.f);
    bf16x4 o = {(bf16)x0, (bf16)x1, (bf16)x2, (bf16)x3};
    int bi = b * 36 + gl;
    long rowp = (long)(bi >> 2) * 144 + j * 4 + (bi & 3);
    *(bf16x4*)(z + ((long)(kq * 4 + kcl) * ZROWS + rowp) * 32 + x4 * 4) = o;
  }
}

// ---------------- stage 5: main fused GEMM + register max + residual ----------------
// R15: R13 (144x128, 3 blocks/CU) = 140.4 us, MfmaUtil 59, Occ 39. LDS-port accounting:
// 62.5 KB/kstep-block (A-read 4x9 + B 8.2 + writes 17.4) x32x18/CU = 36 MB/140us =
// 256 GB/s = 83% of the 307 GB/s port -> LDS port is now the binding pipe (MFMA floor
// 84 us, LDS floor 117 us). B's LDS round-trip is pure waste: each B byte written+read
// by exactly ONE wave (private 32-col strip). R15 = R13 + B direct global->VGPR
// (mapping verified correct in R11; R11's slowdown came from its asm fences + 3-buf,
// both absent here). Plain __syncthreads skeleton; B prefetched 1 kstep ahead in an
// even/odd unrolled pair (static reg indexing, rule #20); the barrier's implicit
// vmcnt(0) drain makes the prefetched regs ready for free. LDS = A-only dbuf 18 KB.
// New LDS traffic 46 KB/kstep-block -> ~61% port -> balanced vs 84 us MFMA floor.
__launch_bounds__(256, 3)
__global__ void k_main(const bf16* __restrict__ z, const bf16* __restrict__ PTt,
                       const float* __restrict__ mm, float* __restrict__ out) {
  __shared__ bf16 lds[2 * ABUF];   // 18 KB (A only)
  int bid = blockIdx.x;
  int x = bid & 7, t = bid >> 3;
  int dt = t & 15, go = (t >> 4) * 8 + x;   // dt 0..15, go 0..287 (4-bi groups)
  int d0 = dt * NBLK;
  int tid = threadIdx.x, wave = tid >> 6, lane = tid & 63;
  int l15 = lane & 15, qv = lane >> 4;
  int qp_c = qv ^ ((l15 >> 1) & 3);
  int qs = (lane & 3) ^ ((lane >> 3) & 3);
  int lroff = (lane >> 2) * 32 + qs * 8;

  const bf16* gA = z + (long)go * ABUF + wave * 1024 + lroff;
  int lA = wave * 1024;
  // direct B: lane(l15,qv) reads PTt[kc][d0 + wave*32 + nt*16 + l15][qv*8 .. +7]
  const bf16* gBr = PTt + (long)(d0 + wave * 32 + l15) * 32 + qv * 8;

  int sbuf = 0;
  auto stageA = [&]() {
    bf16* db = lds + sbuf * ABUF;
    gl_lds16(gA, db + lA);
    gl_lds16(gA + 512, db + lA + 512);
    if (wave == 0) gl_lds16(gA + 4096, db + 4096);
    gA += (long)ZROWS * 32;
    sbuf ^= 1;
  };

  bf16x8 pa[2], pb[2];
  auto loadB = [&](int kcb, bf16x8 (&p)[2]) {
    const bf16* src = gBr + (long)kcb * 65536;
    p[0] = *(const bf16x8*)(src);
    p[1] = *(const bf16x8*)(src + 512);
  };

  f32x4 acc[9][2] = {};
  stageA();
  loadB(0, pa);
  for (int kc = 0; kc < 32; kc += 2) {
    // ---- even kstep (uses pa, LDS buf 0) ----
    __syncthreads();                       // A(kc) staged; drains B prefetch too
    if (kc < 31) { stageA(); loadB(kc + 1, pb); }
    {
      const bf16* cur = lds;               // (kc&1)==0
#pragma unroll
      for (int mt = 0; mt < 9; mt++) {
        bf16x8 av = *(const bf16x8*)(cur + (mt * 16 + l15) * 32 + qp_c * 8);
        acc[mt][0] = __builtin_amdgcn_mfma_f32_16x16x32_bf16(av, pa[0], acc[mt][0], 0, 0, 0);
        acc[mt][1] = __builtin_amdgcn_mfma_f32_16x16x32_bf16(av, pa[1], acc[mt][1], 0, 0, 0);
      }
    }
    // ---- odd kstep (uses pb, LDS buf 1) ----
    __syncthreads();
    if (kc < 30) { stageA(); loadB(kc + 2, pa); }
    {
      const bf16* cur = lds + ABUF;        // (kc&1)==1
#pragma unroll
      for (int mt = 0; mt < 9; mt++) {
        bf16x8 av = *(const bf16x8*)(cur + (mt * 16 + l15) * 32 + qp_c * 8);
        acc[mt][0] = __builtin_amdgcn_mfma_f32_16x16x32_bf16(av, pb[0], acc[mt][0], 0, 0, 0);
        acc[mt][1] = __builtin_amdgcn_mfma_f32_16x16x32_bf16(av, pb[1], acc[mt][1], 0, 0, 0);
      }
    }
  }

  // epilogue: row-in-block = mt*16 + qv*4 + r = j*4 + g -> g = r, j = mt*4 + qv.
#pragma unroll
  for (int nt = 0; nt < 2; nt++) {
    float mx[4];
#pragma unroll
    for (int r = 0; r < 4; r++) {
      mx[r] = acc[0][nt][r];
#pragma unroll
      for (int mt = 1; mt < 9; mt++) mx[r] = fmaxf(mx[r], acc[mt][nt][r]);
      mx[r] = fmaxf(mx[r], __shfl_xor(mx[r], 16, 64));
      mx[r] = fmaxf(mx[r], __shfl_xor(mx[r], 32, 64));
    }
    if (lane < 16) {
      int col = d0 + wave * 32 + nt * 16 + lane;
#pragma unroll
      for (int r = 0; r < 4; r++) {
        long oa = (long)(go * 4 + r) * DD + col;
        out[oa] = mx[r] + mm[oa];
      }
    }
  }
}

// ---------------- launcher ----------------
extern "C" void kernel_launch(void* const* d_in, const int* in_sizes, int n_in,
                              void* d_out, int out_size, void* d_ws, size_t ws_size,
                              hipStream_t stream) {
  const float* mm     = (const float*)d_in[0];
  const float* coords = (const float*)d_in[1];
  const float* U_feat = (const float*)d_in[2];
  const float* V_feat = (const float*)d_in[3];
  const float* P_feat = (const float*)d_in[4];
  const float* U_coord= (const float*)d_in[5];
  const float* V_coord= (const float*)d_in[6];
  const float* P_coord= (const float*)d_in[7];
  float* out = (float*)d_out;

  char* ws = (char*)d_ws;
  bf16* z   = (bf16*)(ws + 0);                 //  84,934,656 B  [kc][41472 row'][32]
  bf16* PTt = (bf16*)(ws + 84934656);          //   4,194,304 B  [kc][2048][32]
  bf16* mmb = (bf16*)(ws + 89128960);          //   4,718,592 B
  bf16* UT  = (bf16*)(ws + 93847552);          //   2,097,152 B  [512][2048]
  bf16* VT  = (bf16*)(ws + 95944704);          //   2,097,152 B
  float* uf = (float*)(ws + 98041856);         //   2,359,296 B
  float* vf = (float*)(ws + 100401152);
  float* uc = (float*)(ws + 102760448);
  float* vc = (float*)(ws + 105119744);
  float* uf2= (float*)(ws + 107479040);
  float* vf2= (float*)(ws + 109838336);        // end 112,197,632

  k_prep<<<dim3(7552), dim3(256), 0, stream>>>(mm, coords, U_feat, V_feat, P_feat,
                                               U_coord, V_coord, P_coord,
                                               mmb, UT, VT, PTt, uc, vc);
  k_gemm_uv<<<dim3(18, 4, 4), dim3(256), 0, stream>>>(mmb, UT, VT, uf, vf, uf2, vf2);
  k_build_z<<<dim3(8, 32, 8), dim3(256), 0, stream>>>(uc, vc, uf, vf, uf2, vf2, z);
  k_main<<<dim3(4608), dim3(256), 0, stream>>>(z, PTt, mm, out);
}

// Round 8
// 252.486 us; speedup vs baseline: 1.0738x; 1.0738x over previous
//
#include <hip/hip_runtime.h>

// Problem constants
#define BI    1152   // B*N = 32*36
#define NREG  36
#define DD    2048
#define RR    512
#define KK    1024   // 2*R
#define ZROWS (BI*NREG)        // 41472
#define MBLK  144              // 4 bi, rows interleaved j*4+g
#define NBLK  128
#define ABUF  (MBLK*32)        // 4608 elems (9 KB)
#define BBUF  (NBLK*32)        // 4096 elems (8 KB)
#define BUFE  (ABUF+BBUF)      // 8704 elems = 17 KB per buffer

typedef __bf16 bf16;
typedef __bf16 bf16x8 __attribute__((ext_vector_type(8)));
typedef __bf16 bf16x4 __attribute__((ext_vector_type(4)));
typedef float  f32x4  __attribute__((ext_vector_type(4)));

__device__ __forceinline__ void gl_lds16(const void* g, void* l) {
  __builtin_amdgcn_global_load_lds(
      (const __attribute__((address_space(1))) unsigned int*)g,
      (__attribute__((address_space(3))) unsigned int*)l, 16, 0, 0);
}

// ---------------- fused prep: cvt_mm + transpose_uv + transpose_pt + uvcoord -------
__global__ void k_prep(const float* __restrict__ mm, const float* __restrict__ coords,
                       const float* __restrict__ U_feat, const float* __restrict__ V_feat,
                       const float* __restrict__ P_feat, const float* __restrict__ U_coord,
                       const float* __restrict__ V_coord, const float* __restrict__ P_coord,
                       bf16* __restrict__ mmb, bf16* __restrict__ UT, bf16* __restrict__ VT,
                       bf16* __restrict__ PTt, float* __restrict__ uc, float* __restrict__ vc) {
  __shared__ float tile[32][33];
  int bid = blockIdx.x, tid = threadIdx.x;
  if (bid < 2304) {
    int i = bid * 256 + tid;
    float4 v = ((const float4*)mm)[i];
    bf16x4 o = {(bf16)v.x, (bf16)v.y, (bf16)v.z, (bf16)v.w};
    ((bf16x4*)mmb)[i] = o;
  } else if (bid < 4352) {
    int rel = bid - 2304;
    int zz = rel >> 10, rr = rel & 1023;
    int c0 = (rr & 15) * 32, r0 = (rr >> 4) * 32;     // cols 512, rows 2048
    const float* in = zz ? V_feat : U_feat;
    bf16* outp = zz ? VT : UT;
    int tx = tid & 31, ty = tid >> 5;
#pragma unroll
    for (int k = 0; k < 4; k++)
      tile[ty + 8 * k][tx] = in[(long)(r0 + ty + 8 * k) * 512 + c0 + tx];
    __syncthreads();
#pragma unroll
    for (int k = 0; k < 4; k++)
      outp[(long)(c0 + ty + 8 * k) * 2048 + r0 + tx] = (bf16)tile[tx][ty + 8 * k];
  } else if (bid < 6400) {
    int rel = bid - 4352;
    int zz = rel >> 10, rr = rel & 1023;
    int c0 = (rr & 63) * 32, r0 = (rr >> 6) * 32;     // cols 2048, rows 512
    const float* in = zz ? P_feat : P_coord;
    int koff = zz * 512;
    int tx = tid & 31, ty = tid >> 5;
#pragma unroll
    for (int k = 0; k < 4; k++)
      tile[ty + 8 * k][tx] = in[(long)(r0 + ty + 8 * k) * 2048 + c0 + tx];
    __syncthreads();
    int kc = (koff + r0) >> 5;
#pragma unroll
    for (int k = 0; k < 4; k++) {
      int d = c0 + ty + 8 * k;
      PTt[((long)kc * 2048 + d) * 32 + tx] = (bf16)tile[tx][ty + 8 * k];
    }
  } else {
    int g = bid - 6400;
    float c0 = coords[g * 4 + 0], c1 = coords[g * 4 + 1];
    float c2 = coords[g * 4 + 2], c3 = coords[g * 4 + 3];
#pragma unroll
    for (int i = 0; i < 2; i++) {
      int r = tid + i * 256;
      uc[g * RR + r] = c0 * U_coord[r] + c1 * U_coord[RR + r] + c2 * U_coord[2 * RR + r] + c3 * U_coord[3 * RR + r];
      vc[g * RR + r] = c0 * V_coord[r] + c1 * V_coord[RR + r] + c2 * V_coord[2 * RR + r] + c3 * V_coord[3 * RR + r];
    }
  }
}

// ------- stage 3: uf/vf partials (split-K=2), 64x128 tile, dbuf -------
__launch_bounds__(256)
__global__ void k_gemm_uv(const bf16* __restrict__ mmb, const bf16* __restrict__ UT,
                          const bf16* __restrict__ VT, float* __restrict__ uf,
                          float* __restrict__ vf, float* __restrict__ uf2,
                          float* __restrict__ vf2) {
  __shared__ bf16 lds2[2][6144];   // per buf: A 64x32 (2048) + B 128x32 (4096)
  int uv = blockIdx.z >> 1, kh = blockIdx.z & 1;
  const bf16* Bmat = uv ? VT : UT;
  float* outp = uv ? (kh ? vf2 : vf) : (kh ? uf2 : uf);
  int m0 = blockIdx.x * 64, n0 = blockIdx.y * 128;
  int kbase = kh * 1024;
  int tid = threadIdx.x, wave = tid >> 6, lane = tid & 63;
  int l15 = lane & 15, qv = lane >> 4;
  int qp_c = qv ^ ((l15 >> 1) & 3);
  int qs = (lane & 3) ^ ((lane >> 3) & 3);

  const bf16* gA = mmb + (long)(m0 + wave * 16 + (lane >> 2)) * 2048 + kbase + qs * 8;
  const bf16* gB = Bmat + (long)(n0 + wave * 32 + (lane >> 2)) * 2048 + kbase + qs * 8;
  int lA = wave * 512;
  int lB = 2048 + wave * 1024;

  auto stage = [&](int buf, int k0) {
    bf16* db = &lds2[buf][0];
    gl_lds16(gA + k0, db + lA);
    gl_lds16(gB + k0, db + lB);
    gl_lds16(gB + 16 * 2048 + k0, db + lB + 512);
  };

  f32x4 acc[4][2] = {};
  stage(0, 0);
  for (int k0 = 0; k0 < 1024; k0 += 32) {
    int cur = (k0 >> 5) & 1;
    __syncthreads();
    if (k0 + 32 < 1024) stage(cur ^ 1, k0 + 32);
    bf16x8 a[4], b[2];
#pragma unroll
    for (int mt = 0; mt < 4; mt++)
      a[mt] = *(const bf16x8*)(&lds2[cur][0] + (mt * 16 + l15) * 32 + qp_c * 8);
#pragma unroll
    for (int nt = 0; nt < 2; nt++)
      b[nt] = *(const bf16x8*)(&lds2[cur][2048] + (wave * 32 + nt * 16 + l15) * 32 + qp_c * 8);
#pragma unroll
    for (int mt = 0; mt < 4; mt++)
#pragma unroll
      for (int nt = 0; nt < 2; nt++)
        acc[mt][nt] = __builtin_amdgcn_mfma_f32_16x16x32_bf16(a[mt], b[nt], acc[mt][nt], 0, 0, 0);
  }
#pragma unroll
  for (int mt = 0; mt < 4; mt++)
#pragma unroll
    for (int nt = 0; nt < 2; nt++)
#pragma unroll
      for (int r = 0; r < 4; r++) {
        int row = m0 + mt * 16 + qv * 4 + r;
        int col = n0 + wave * 32 + nt * 16 + l15;
        outp[(long)row * RR + col] = acc[mt][nt][r];
      }
}

// ------- stage 4: z_t[kc][row'][32], row' = (bi>>2)*144 + j*4 + (bi&3) -------
// R16: slice staging. R12's 8-way z-split made every block stage the FULL 36x128 uv
// tile (73.7 KB) while using 1/10.7 of it (one kcl of 4, half the i-rows) -> 75 MB
// redundant global reads across 2048 blocks. Now stage exactly the needed slice:
// u 18 rows x 32k + v 36 rows x 32k f32 = 6.9 KB/block -> 14 MB total, LDS 10x smaller.
// Mapping (bz = blockIdx.z): kcl = bz>>1, rowhalf = bz&1; item = gl(18) x j(36) x x4(8).
__global__ void k_build_z(const float* __restrict__ uc, const float* __restrict__ vc,
                          const float* __restrict__ uf, const float* __restrict__ vf,
                          const float* __restrict__ uf2, const float* __restrict__ vf2,
                          bf16* __restrict__ z) {
  __shared__ float uL[18 * 32];
  __shared__ float vL[36 * 32];
  int kq = blockIdx.x, b = blockIdx.y, bz = blockIdx.z, tid = threadIdx.x;
  int kcl = bz >> 1, rowhalf = bz & 1;
  int koff = (kq & 3) * 128 + kcl * 32;      // k-offset within the 512-wide half
  // stage: 18 u-rows (i = rowhalf*18 + r) and 36 v-rows, 32 floats each.
  // 18*8 + 36*8 = 432 float4 chunks; threads 0..431 hit via two strides.
  for (int i = tid; i < 432; i += 256) {
    float4 val;
    if (i < 144) {
      int r = i >> 3, ch = i & 7;
      long src = (long)(b * 36 + rowhalf * 18 + r) * RR + koff + ch * 4;
      if (kq < 4) val = *(const float4*)(uc + src);
      else {
        float4 a1 = *(const float4*)(uf + src), a2 = *(const float4*)(uf2 + src);
        val.x = a1.x + a2.x; val.y = a1.y + a2.y; val.z = a1.z + a2.z; val.w = a1.w + a2.w;
      }
      *(float4*)&uL[r * 32 + ch * 4] = val;
    } else {
      int iv = i - 144;
      int r = iv >> 3, ch = iv & 7;
      long src = (long)(b * 36 + r) * RR + koff + ch * 4;
      if (kq < 4) val = *(const float4*)(vc + src);
      else {
        float4 b1 = *(const float4*)(vf + src), b2 = *(const float4*)(vf2 + src);
        val.x = b1.x + b2.x; val.y = b1.y + b2.y; val.z = b1.z + b2.z; val.w = b1.w + b2.w;
      }
      *(float4*)&vL[r * 32 + ch * 4] = val;
    }
  }
  __syncthreads();
  int kc = kq * 4 + kcl;
  // items: gl(18) x j(36) x x4(8) = 5184
  for (int item = tid; item < 5184; item += 256) {
    int gl = item / 288;
    int rem = item - gl * 288;
    int j = rem >> 3, x4 = rem & 7;
    float4 u4 = *(const float4*)&uL[gl * 32 + x4 * 4];
    float4 v4 = *(const float4*)&vL[j * 32 + x4 * 4];
    float x0 = fmaxf(u4.x * v4.x, 0.f), x1 = fmaxf(u4.y * v4.y, 0.f);
    float x2 = fmaxf(u4.z * v4.z, 0.f), x3 = fmaxf(u4.w * v4.w, 0.f);
    bf16x4 o = {(bf16)x0, (bf16)x1, (bf16)x2, (bf16)x3};
    int bi = b * 36 + rowhalf * 18 + gl;
    long rowp = (long)(bi >> 2) * 144 + j * 4 + (bi & 3);
    *(bf16x4*)(z + ((long)kc * ZROWS + rowp) * 32 + x4 * 4) = o;
  }
}

// ---------------- stage 5: main fused GEMM + register max + residual ----------------
// R16: k_main reverted to the R13 version (measured 140.4 us, MfmaUtil 59, Occ 39,
// 3 blocks/CU, conflicts 0) — the best of 6 measured variants. Hand-scheduling (R10),
// B direct-to-reg (R11 w/ fences, R15 plain) all regressed 10-20%: B stays in LDS via
// global_load_lds. Kernel is LDS-port-bound (~83% port util; MFMA floor 84 us,
// LDS floor ~117 us at 62.5 KB/kstep-block).
__launch_bounds__(256, 3)
__global__ void k_main(const bf16* __restrict__ z, const bf16* __restrict__ PTt,
                       const float* __restrict__ mm, float* __restrict__ out) {
  __shared__ bf16 lds[2 * BUFE];   // 34.8 KB
  int bid = blockIdx.x;
  int x = bid & 7, t = bid >> 3;
  int dt = t & 15, go = (t >> 4) * 8 + x;   // dt 0..15, go 0..287 (4-bi groups)
  int d0 = dt * NBLK;
  int tid = threadIdx.x, wave = tid >> 6, lane = tid & 63;
  int l15 = lane & 15, qv = lane >> 4;
  int qp_c = qv ^ ((l15 >> 1) & 3);
  int qs = (lane & 3) ^ ((lane >> 3) & 3);
  int lroff = (lane >> 2) * 32 + qs * 8;

  const bf16* gA = z + (long)go * ABUF + wave * 1024 + lroff;
  const bf16* gB = PTt + (long)d0 * 32 + wave * 1024 + lroff;
  int lA = wave * 1024;
  int lB = ABUF + wave * 1024;

  int sbuf = 0;
  auto stage = [&]() {
    bf16* db = lds + sbuf * BUFE;
    gl_lds16(gA, db + lA);
    gl_lds16(gA + 512, db + lA + 512);
    if (wave == 0) gl_lds16(gA + 4096, db + 4096);
    gl_lds16(gB, db + lB);
    gl_lds16(gB + 512, db + lB + 512);
    gA += (long)ZROWS * 32;
    gB += 2048L * 32;
    sbuf ^= 1;
  };

  f32x4 acc[9][2] = {};
  stage();
  for (int kc = 0; kc < 32; kc++) {
    __syncthreads();
    if (kc < 31) stage();
    const bf16* cur = lds + (kc & 1) * BUFE;
    bf16x8 b[2];
#pragma unroll
    for (int nt = 0; nt < 2; nt++)
      b[nt] = *(const bf16x8*)(cur + ABUF + (wave * 32 + nt * 16 + l15) * 32 + qp_c * 8);
#pragma unroll
    for (int mt = 0; mt < 9; mt++) {
      bf16x8 av = *(const bf16x8*)(cur + (mt * 16 + l15) * 32 + qp_c * 8);
#pragma unroll
      for (int nt = 0; nt < 2; nt++)
        acc[mt][nt] = __builtin_amdgcn_mfma_f32_16x16x32_bf16(av, b[nt], acc[mt][nt], 0, 0, 0);
    }
  }

  // epilogue: row-in-block = mt*16 + qv*4 + r = j*4 + g -> g = r, j = mt*4 + qv.
#pragma unroll
  for (int nt = 0; nt < 2; nt++) {
    float mx[4];
#pragma unroll
    for (int r = 0; r < 4; r++) {
      mx[r] = acc[0][nt][r];
#pragma unroll
      for (int mt = 1; mt < 9; mt++) mx[r] = fmaxf(mx[r], acc[mt][nt][r]);
      mx[r] = fmaxf(mx[r], __shfl_xor(mx[r], 16, 64));
      mx[r] = fmaxf(mx[r], __shfl_xor(mx[r], 32, 64));
    }
    if (lane < 16) {
      int col = d0 + wave * 32 + nt * 16 + lane;
#pragma unroll
      for (int r = 0; r < 4; r++) {
        long oa = (long)(go * 4 + r) * DD + col;
        out[oa] = mx[r] + mm[oa];
      }
    }
  }
}

// ---------------- launcher ----------------
extern "C" void kernel_launch(void* const* d_in, const int* in_sizes, int n_in,
                              void* d_out, int out_size, void* d_ws, size_t ws_size,
                              hipStream_t stream) {
  const float* mm     = (const float*)d_in[0];
  const float* coords = (const float*)d_in[1];
  const float* U_feat = (const float*)d_in[2];
  const float* V_feat = (const float*)d_in[3];
  const float* P_feat = (const float*)d_in[4];
  const float* U_coord= (const float*)d_in[5];
  const float* V_coord= (const float*)d_in[6];
  const float* P_coord= (const float*)d_in[7];
  float* out = (float*)d_out;

  char* ws = (char*)d_ws;
  bf16* z   = (bf16*)(ws + 0);                 //  84,934,656 B  [kc][41472 row'][32]
  bf16* PTt = (bf16*)(ws + 84934656);          //   4,194,304 B  [kc][2048][32]
  bf16* mmb = (bf16*)(ws + 89128960);          //   4,718,592 B
  bf16* UT  = (bf16*)(ws + 93847552);          //   2,097,152 B  [512][2048]
  bf16* VT  = (bf16*)(ws + 95944704);          //   2,097,152 B
  float* uf = (float*)(ws + 98041856);         //   2,359,296 B
  float* vf = (float*)(ws + 100401152);
  float* uc = (float*)(ws + 102760448);
  float* vc = (float*)(ws + 105119744);
  float* uf2= (float*)(ws + 107479040);
  float* vf2= (float*)(ws + 109838336);        // end 112,197,632

  k_prep<<<dim3(7552), dim3(256), 0, stream>>>(mm, coords, U_feat, V_feat, P_feat,
                                               U_coord, V_coord, P_coord,
                                               mmb, UT, VT, PTt, uc, vc);
  k_gemm_uv<<<dim3(18, 4, 4), dim3(256), 0, stream>>>(mmb, UT, VT, uf, vf, uf2, vf2);
  k_build_z<<<dim3(8, 32, 8), dim3(256), 0, stream>>>(uc, vc, uf, vf, uf2, vf2, z);
  k_main<<<dim3(4608), dim3(256), 0, stream>>>(z, PTt, mm, out);
}